// Round 4
// baseline (242.717 us; speedup 1.0000x reference)
//
#include <hip/hip_runtime.h>
#include <hip/hip_bf16.h>

// Problem constants
#define NB 256
#define NACT 21
#define NA 8192
#define NE 262144
#define CSR_CAP 128
#define LOG2E 1.44269504f

#if __has_builtin(__builtin_amdgcn_exp2f)
#define EXP2F(x) __builtin_amdgcn_exp2f(x)
#else
#define EXP2F(x) exp2f(x)
#endif

typedef __attribute__((ext_vector_type(8))) short short8;
typedef __attribute__((ext_vector_type(4))) float float4v;

__device__ inline float wsum64(float v) {
#pragma unroll
  for (int m = 32; m > 0; m >>= 1) v += __shfl_xor(v, m, 64);
  return v;
}

__device__ inline unsigned short f2bf(float f) {
  union { __hip_bfloat16 h; unsigned short u; } cv;
  cv.h = __float2bfloat16(f);
  return cv.u;
}

// ---------------- k_init: zero cnt (action passthrough lives in k_he) ----------------
__global__ __launch_bounds__(512) void k_init(int* cnt) {
  int i = blockIdx.x * 512 + threadIdx.x;  // 16*512 = 8192
  cnt[i] = 0;
}

// ---------------- k_pc: conv (blocks 0..511, 2 per image) + prep (blocks 512..1023) ----------------
// conv: conv1 (duplicated, trivial) + conv2 half (32 ocs) per block -> 2 blocks/image for grid width.
// prep: CSR build + fcw->bf16 + W2 transpose/partials.
__global__ __launch_bounds__(512, 2) void k_pc(
    const int* __restrict__ edges, const float* __restrict__ fcw,
    const float* __restrict__ g2w, const float* __restrict__ g2b,
    unsigned short* fcwbf, unsigned short* w2t, float* wpart, int* cnt, int* csr,
    const float* __restrict__ x, const float* __restrict__ c1w, const float* __restrict__ c1b,
    const float* __restrict__ c2w, const float* __restrict__ c2b, unsigned short* h1024bf) {
  __shared__ float sm[5773];  // conv: xs[845] w1s[1440] c1s[1152] w2s[32*73=2336]; prep: red[16][17]+b2s[16]
  int t = threadIdx.x;
  if (blockIdx.x >= 512) {  // ---- prep ----
    float (*red)[17] = (float(*)[17])sm;
    float* b2s = sm + 272;
    int blk = blockIdx.x - 512;
    {  // CSR: 1 edge per thread (512*512 = NE)
      int e = blk * 512 + t;
      int s = edges[2 * e], d = edges[2 * e + 1];
      int slot = atomicAdd(&cnt[d], 1);
      if (slot < CSR_CAP) csr[d * CSR_CAP + slot] = s;
    }
    {  // fcw -> bf16: 2 floats per thread
      int base = (blk * 512 + t) * 2;
      float2 v = *(const float2*)&fcw[base];
      fcwbf[base + 0] = f2bf(v.x);
      fcwbf[base + 1] = f2bf(v.y);
    }
    {  // W2: block owns 16 cols; w2t[j][k] = W2[k][j] bf16; column partial sums
      if (t < 256) {
        int jj = t >> 4, k = t & 15;
        int j = blk * 16 + jj;
        float w = g2w[k * 8192 + j];
        w2t[j * 16 + k] = f2bf(w);
        red[jj][k] = w;
      }
      if (t < 16) b2s[t] = g2b[blk * 16 + t];
      __syncthreads();
      if (t < 16) {
        float s = 0.0f;
#pragma unroll
        for (int q = 0; q < 16; q++) s += red[q][t];
        wpart[blk * 17 + t] = s;
      } else if (t == 16) {
        float s = 0.0f;
#pragma unroll
        for (int q = 0; q < 16; q++) s += b2s[q];
        wpart[blk * 17 + 16] = s;
      }
    }
  } else {  // ---- conv: img = b>>1, ocs [half*32, half*32+32) ----
    float* xs = sm;
    float* w1s = sm + 845;
    float* c1s = sm + 2285;
    float* w2s = sm + 3437;  // 32*73
    int img = blockIdx.x >> 1, half = blockIdx.x & 1;
    for (int i = t; i < 845; i += 512) xs[i] = x[img * 845 + i];
    for (int i = t; i < 1440; i += 512) w1s[i] = c1w[i];
    __syncthreads();
    for (int idx = t; idx < 1152; idx += 512) {
      int oc = idx / 36, p = idx - oc * 36;
      int oy = p / 6, ox = p - oy * 6;
      float acc = c1b[oc];
      const float* wp = &w1s[oc * 45];
#pragma unroll
      for (int ic = 0; ic < 5; ic++)
#pragma unroll
        for (int ky = 0; ky < 3; ky++)
#pragma unroll
          for (int kx = 0; kx < 3; kx++)
            acc += xs[ic * 169 + (oy * 2 + ky) * 13 + ox * 2 + kx] * wp[ic * 9 + ky * 3 + kx];
      c1s[idx] = fmaxf(acc, 0.0f);
    }
    int p = t & 15, ocl = t >> 4;  // 1 output per thread: 16 pos x 32 oc
    int oy = p >> 2, ox = p & 3;
    int oc = half * 32 + ocl;
    float a0 = c2b[oc];
    for (int icb = 0; icb < 32; icb += 8) {
      __syncthreads();
      for (int i = t; i < 2304; i += 512) {  // 32 oc x 72
        int o = i / 72, r = i - o * 72;
        w2s[o * 73 + r] = c2w[(half * 32 + o) * 288 + icb * 9 + r];
      }
      __syncthreads();
#pragma unroll
      for (int ic = 0; ic < 8; ic++) {
#pragma unroll
        for (int ky = 0; ky < 3; ky++) {
#pragma unroll
          for (int kx = 0; kx < 3; kx++) {
            float cvv = c1s[(icb + ic) * 36 + (oy + ky) * 6 + ox + kx];
            a0 += cvv * w2s[ocl * 73 + ic * 9 + ky * 3 + kx];
          }
        }
      }
    }
    h1024bf[img * 1024 + oc * 16 + p] = f2bf(fmaxf(a0, 0.0f));
  }
}

// ---------------- k_fc: FC via bf16 MFMA (1 tile/block, K-split 4) + dinv/xs2 + wsf ----------------
__global__ __launch_bounds__(256, 4) void k_fc(
    const int* __restrict__ cnt, const float* __restrict__ x_msg,
    const unsigned short* __restrict__ h1024bf, const unsigned short* __restrict__ fcwbf,
    const float* __restrict__ fcb, const float* __restrict__ wpart,
    float* hidden, float* dinv, float* xs2, float* wsf) {
  __shared__ float red[4][256];
  int t = threadIdx.x, blk = blockIdx.x;
  if (blk == 512) {  // parallel wsf reduce: 272 threads x 32 strided loads
    float* part = &red[0][0];
    if (t < 272) {
      int q = t / 17, c = t - q * 17;
      float s = 0.0f;
      for (int r = q; r < 512; r += 16) s += wpart[r * 17 + c];
      part[t] = s;
    }
    __syncthreads();
    if (t < 17) {
      float s = 0.0f;
#pragma unroll
      for (int q = 0; q < 16; q++) s += part[q * 17 + t];
      wsf[t] = s;
    }
    return;
  }
  int wave = t >> 6, lane = t & 63;
  if (blk < 32) {
    int i = blk * 256 + t;
    float d = rsqrtf((float)cnt[i] + 1.0f);
    dinv[i] = d;
    xs2[i] = d * x_msg[i];
  }
  int tr = blk >> 5, tc = blk & 31;  // 16 row-tiles x 32 col-tiles
  int m = lane & 15, quad = lane >> 4;
  const unsigned short* ap = &h1024bf[(tr * 16 + m) * 1024 + wave * 256 + quad * 8];
  const unsigned short* bp = &fcwbf[(tc * 16 + m) * 1024 + wave * 256 + quad * 8];
  float4v acc = {0.0f, 0.0f, 0.0f, 0.0f};
#pragma unroll
  for (int i = 0; i < 8; i++) {
    short8 a = *(const short8*)(ap + i * 32);
    short8 b = *(const short8*)(bp + i * 32);
    acc = __builtin_amdgcn_mfma_f32_16x16x32_bf16(a, b, acc, 0, 0, 0);
  }
#pragma unroll
  for (int r = 0; r < 4; r++) red[wave][(quad * 4 + r) * 16 + m] = acc[r];
  __syncthreads();
  {  // reduce 4 K-slices + bias + relu
    float s = red[0][t] + red[1][t] + red[2][t] + red[3][t];
    int gr = tr * 16 + (t >> 4);
    int gc = tc * 16 + (t & 15);
    hidden[gr * 512 + gc] = fmaxf(s + fcb[gc], 0.0f);
  }
}

// ---------------- k_he: head (blocks 0..63) | enc (blocks 64..511) ----------------
__global__ __launch_bounds__(512, 2) void k_he(
    const float* __restrict__ hidden, const float* __restrict__ muw,
    const float* __restrict__ mub, const float* __restrict__ msgw,
    const float* __restrict__ msgb, const float* __restrict__ dinv,
    const int* __restrict__ action, float* es2, float* out) {
  __shared__ float muT[10752];
  __shared__ float hrows[2048];
  int t = threadIdx.x, blk = blockIdx.x;
  int wave = t >> 6, lane = t & 63;
  if (blk < 64) {  // head: 4 batch rows per block
    int b0 = blk * 4;
    for (int i = t; i < 10752; i += 512) {
      int a = i >> 9, k = i & 511;
      muT[k * 21 + a] = muw[i];
    }
    for (int i = t; i < 2048; i += 512) hrows[i] = hidden[b0 * 512 + i];
    __syncthreads();
    if (wave < 4) {
      int b = b0 + wave;
      float logit = -1e30f;
      if (lane < NACT) {
        float acc = mub[lane];
        const float* hr = &hrows[wave * 512];
        for (int k = 0; k < 512; k++) acc += hr[k] * muT[k * 21 + lane];
        logit = acc;
      }
      float m = logit;
#pragma unroll
      for (int s = 32; s > 0; s >>= 1) m = fmaxf(m, __shfl_xor(m, s, 64));
      float e = (lane < NACT) ? __expf(logit - m) : 0.0f;
      float se = wsum64(e);
      float swl = wsum64(e * logit);
      float lse = m + __logf(se);
      int act = action[b];
      if (lane == 0) {
        out[b] = (float)act;                  // action passthrough
        out[8704 + b] = lse - swl / se;       // entropy
      }
      if (lane == act) out[8448 + b] = logit - lse;  // log_prob
    }
  } else {  // enc: es2[j] = dinv[j] * (hidden[0].msg_w[j] + msgb[j])
    int wg = (blk - 64) * 8 + wave;  // 0..3583
    for (int j = wg; j < NA; j += 3584) {
      const float* wp = &msgw[j * 512 + lane * 8];
      float4 w0 = *(const float4*)(wp);
      float4 w1 = *(const float4*)(wp + 4);
      float4 h0 = *(const float4*)&hidden[lane * 8];
      float4 h1 = *(const float4*)&hidden[lane * 8 + 4];
      float s = w0.x * h0.x + w0.y * h0.y + w0.z * h0.z + w0.w * h0.w +
                w1.x * h1.x + w1.y * h1.y + w1.z * h1.z + w1.w * h1.w;
      s = wsum64(s);
      if (lane == 0) es2[j] = dinv[j] * (s + msgb[j]);
    }
  }
}

// ---------------- k_g1: GCN1 gather (2 rows per wave, 512 blocks) ----------------
__global__ __launch_bounds__(512, 4) void k_g1(
    const int* __restrict__ cnt, const int* __restrict__ csr,
    const float* __restrict__ dinv, const float* __restrict__ xs2,
    const float* __restrict__ es2, const float* __restrict__ g1w,
    const float* __restrict__ g1b, float* gbuf2) {
  int t = threadIdx.x, blk = blockIdx.x;
  int wave = t >> 6, lane = t & 63;
  int wg = blk * 8 + wave;  // 0..4095
#pragma unroll
  for (int rr = 0; rr < 2; rr++) {
    int i = wg * 2 + rr;
    int ci = min(cnt[i], CSR_CAP);
    float di = dinv[i];
    float a0 = 0.0f, a1 = 0.0f;
    for (int e = lane; e < ci; e += 64) {
      int s = csr[i * CSR_CAP + e];
      a0 += xs2[s];
      a1 += es2[s];
    }
    // self-loop coeff di^2: di*(sum_s dinv[s]x[s] + dinv[i]x[i])
    float f0 = (wsum64(a0) + xs2[i]) * di;
    float f1 = (wsum64(a1) + es2[i]) * di;
    if (lane < 16) {
      float gv = fmaxf(f0 * g1w[lane] + f1 * g1w[16 + lane] + g1b[lane], 0.0f);
      gbuf2[i * 16 + lane] = di * gv;
    }
  }
}

// ---------------- k_msg: GCN2 gather + MFMA scores + sum-exp (16 rows/block, 512 blocks) ----------------
__global__ __launch_bounds__(512, 2) void k_msg(
    const int* __restrict__ cnt, const int* __restrict__ csr,
    const float* __restrict__ dinv, const float* __restrict__ gbuf2,
    const float* __restrict__ wsf, const unsigned short* __restrict__ w2t,
    const float* __restrict__ g2b, float* out) {
  __shared__ __align__(16) unsigned short vbf[256];
  __shared__ float vf[256];
  __shared__ float pl[2048];
  __shared__ float sl[128];
  __shared__ float wsfs[17];
  int t = threadIdx.x, blk = blockIdx.x;
  int wave = t >> 6, lane = t & 63;
  int rowbase = blk * 16;
  if (t < 17) wsfs[t] = wsf[t];
  {  // gather 16 V rows: 8 waves x 2 rows; lanes = 4 edge-groups x 16 cols
    int eq = lane >> 4, c = lane & 15;
#pragma unroll
    for (int rr = 0; rr < 2; rr++) {
      int il = wave * 2 + rr;
      int i = rowbase + il;
      int ci = min(cnt[i], CSR_CAP);
      float di = dinv[i];
      float acc = (eq == 0) ? gbuf2[i * 16 + c] : 0.0f;  // self: di*(...+gbuf2[i]) = di^2*g_i
      for (int e = eq; e < ci; e += 4) {
        int s = csr[i * CSR_CAP + e];
        acc += gbuf2[s * 16 + c];
      }
      acc *= di;
      acc += __shfl_xor(acc, 16, 64);
      acc += __shfl_xor(acc, 32, 64);
      if (eq == 0) {
        vf[il * 16 + c] = acc;
        vbf[il * 16 + c] = f2bf(acc * LOG2E);  // pre-scale for exp2
      }
    }
  }
  __syncthreads();
  float myMean = 0.0f;
  if (t < 16) {
    float dot = 0.0f;
#pragma unroll
    for (int c = 0; c < 16; c++) dot += vf[t * 16 + c] * wsfs[c];
    myMean = (dot + wsfs[16]) * (1.0f / 8192.0f);
  }
  {  // scores via MFMA (log2e-scaled) + exp2; each wave owns a 1024-col slice
    int quad = lane >> 4, n = lane & 15;
    int k8 = quad * 8;
    short8 za = {0, 0, 0, 0, 0, 0, 0, 0};
    short8 a1 = za;
    if (quad < 2) a1 = *(const short8*)&vbf[n * 16 + k8];  // K padded 16->32
    float sacc[4];
#pragma unroll
    for (int q = 0; q < 4; q++) sacc[q] = 0.0f;
    int colb = wave * 1024 + n;
    for (int tp = 0; tp < 64; tp += 2) {
      int col1 = colb + tp * 16;
      int col2 = col1 + 16;
      short8 b1 = za, b2 = za;
      if (quad < 2) {
        b1 = *(const short8*)&w2t[col1 * 16 + k8];
        b2 = *(const short8*)&w2t[col2 * 16 + k8];
      }
      float bb1 = g2b[col1] * LOG2E, bb2 = g2b[col2] * LOG2E;
      float4v c1 = {bb1, bb1, bb1, bb1};
      float4v c2 = {bb2, bb2, bb2, bb2};
      float4v s11 = __builtin_amdgcn_mfma_f32_16x16x32_bf16(a1, b1, c1, 0, 0, 0);
      float4v s12 = __builtin_amdgcn_mfma_f32_16x16x32_bf16(a1, b2, c2, 0, 0, 0);
#pragma unroll
      for (int r = 0; r < 4; r++) sacc[r] += EXP2F(s11[r]) + EXP2F(s12[r]);
    }
#pragma unroll
    for (int q = 0; q < 4; q++) {
      int rl = quad * 4 + q;  // C/D row = quad*4+reg
      pl[rl * 128 + wave * 16 + n] = sacc[q];
    }
  }
  __syncthreads();
  if (t < 128) {
    int r = t >> 3, seg = t & 7;
    int base = r * 128 + seg * 16;
    float ll = 0.0f;
#pragma unroll
    for (int i = 0; i < 16; i++) ll += pl[base + i];
    sl[r * 8 + seg] = ll;
  }
  __syncthreads();
  if (t < 16) {
    float ll = 0.0f;
#pragma unroll
    for (int i = 0; i < 8; i++) ll += sl[t * 8 + i];
    out[256 + rowbase + t] = myMean - __logf(ll);  // ll = sum exp(s)
  }
}

extern "C" void kernel_launch(void* const* d_in, const int* in_sizes, int n_in,
                              void* d_out, int out_size, void* d_ws, size_t ws_size,
                              hipStream_t stream) {
  const float* x     = (const float*)d_in[0];
  const float* x_msg = (const float*)d_in[1];
  const int*   edges = (const int*)d_in[2];
  const int*   action= (const int*)d_in[3];
  const float* c1w   = (const float*)d_in[4];
  const float* c1b   = (const float*)d_in[5];
  const float* c2w   = (const float*)d_in[6];
  const float* c2b   = (const float*)d_in[7];
  const float* fcw   = (const float*)d_in[8];
  const float* fcb   = (const float*)d_in[9];
  const float* muw   = (const float*)d_in[10];
  const float* mub   = (const float*)d_in[11];
  const float* msgw  = (const float*)d_in[12];
  const float* msgb  = (const float*)d_in[13];
  const float* g1w   = (const float*)d_in[14];
  const float* g1b   = (const float*)d_in[15];
  const float* g2w   = (const float*)d_in[16];
  const float* g2b   = (const float*)d_in[17];
  float* out = (float*)d_out;  // reference outputs are fp32

  float* ws     = (float*)d_ws;
  unsigned short* h1024bf = (unsigned short*)ws;            // 262144 bf16 = 131072 f
  unsigned short* fcwbf   = (unsigned short*)(ws + 131072); // 524288 bf16 = 262144 f
  float* hidden = ws + 393216;           // 131072
  float* es2    = ws + 524288;           // 8192
  float* dinv   = ws + 532480;           // 8192
  float* xs2    = ws + 540672;           // 8192
  float* gbuf2  = ws + 548864;           // 131072
  float* wpart  = ws + 679936;           // 8704
  unsigned short* w2t = (unsigned short*)(ws + 688640);     // 131072 bf16 = 65536 f
  int*   cnt    = (int*)(ws + 754176);   // 8192 ints
  int*   csr    = (int*)(ws + 762368);   // 1048576 ints -> ends at float-offset 1810944
  float* wsf    = ws + 1810944;          // 17 (AFTER csr — do not overlap!)

  k_init<<<16, 512, 0, stream>>>(cnt);
  k_pc <<<1024, 512, 0, stream>>>(edges, fcw, g2w, g2b, fcwbf, w2t, wpart, cnt, csr,
                                  x, c1w, c1b, c2w, c2b, h1024bf);
  k_fc <<<513, 256, 0, stream>>>(cnt, x_msg, h1024bf, fcwbf, fcb, wpart, hidden, dinv, xs2, wsf);
  k_he <<<512, 512, 0, stream>>>(hidden, muw, mub, msgw, msgb, dinv, action, es2, out);
  k_g1 <<<512, 512, 0, stream>>>(cnt, csr, dinv, xs2, es2, g1w, g1b, gbuf2);
  k_msg<<<512, 512, 0, stream>>>(cnt, csr, dinv, gbuf2, wsf, w2t, g2b, out);
}

// Round 5
// 174.198 us; speedup vs baseline: 1.3933x; 1.3933x over previous
//
#include <hip/hip_runtime.h>
#include <hip/hip_bf16.h>

// Problem constants
#define NB 256
#define NACT 21
#define NA 8192
#define NE 262144
#define CSR_CAP 128
#define LOG2E 1.44269504f

#if __has_builtin(__builtin_amdgcn_exp2f)
#define EXP2F(x) __builtin_amdgcn_exp2f(x)
#else
#define EXP2F(x) exp2f(x)
#endif

typedef __attribute__((ext_vector_type(8))) short short8;
typedef __attribute__((ext_vector_type(4))) float float4v;

__device__ inline float wsum64(float v) {
#pragma unroll
  for (int m = 32; m > 0; m >>= 1) v += __shfl_xor(v, m, 64);
  return v;
}

__device__ inline unsigned short f2bf(float f) {
  union { __hip_bfloat16 h; unsigned short u; } cv;
  cv.h = __float2bfloat16(f);
  return cv.u;
}

// ---------------- k_ic: conv1+im2col (blocks 0..255) | cnt zero (256..271) | c2w->bf16 (272..307) ----------------
__global__ __launch_bounds__(512, 2) void k_ic(
    const float* __restrict__ x, const float* __restrict__ c1w, const float* __restrict__ c1b_,
    const float* __restrict__ c2w, unsigned short* c1b, unsigned short* w2abf, int* cnt) {
  __shared__ float sm[3437];  // xs[845] w1s[1440] c1s[1152]
  int t = threadIdx.x, b = blockIdx.x;
  if (b >= 272) {  // c2w -> bf16 (64*288 = 18432 values)
    int i = (b - 272) * 512 + t;
    w2abf[i] = f2bf(c2w[i]);
    return;
  }
  if (b >= 256) {  // zero cnt
    cnt[(b - 256) * 512 + t] = 0;
    return;
  }
  // conv1 for image b (round-2 code) + im2col write
  float* xs = sm;
  float* w1s = sm + 845;
  float* c1s = sm + 2285;
  for (int i = t; i < 845; i += 512) xs[i] = x[b * 845 + i];
  for (int i = t; i < 1440; i += 512) w1s[i] = c1w[i];
  __syncthreads();
  for (int idx = t; idx < 1152; idx += 512) {
    int oc = idx / 36, p = idx - oc * 36;
    int oy = p / 6, ox = p - oy * 6;
    float acc = c1b_[oc];
    const float* wp = &w1s[oc * 45];
#pragma unroll
    for (int ic = 0; ic < 5; ic++)
#pragma unroll
      for (int ky = 0; ky < 3; ky++)
#pragma unroll
        for (int kx = 0; kx < 3; kx++)
          acc += xs[ic * 169 + (oy * 2 + ky) * 13 + ox * 2 + kx] * wp[ic * 9 + ky * 3 + kx];
    c1s[idx] = fmaxf(acc, 0.0f);
  }
  __syncthreads();
  // im2col: c1b[(b*16+p)*288 + k] = c1s[ic*36 + (oy+ky)*6 + ox+kx]; flat i = p*288+k, coalesced
  for (int i = t; i < 4608; i += 512) {
    int p = i / 288, k = i - p * 288;
    int ic = k / 9, r = k - ic * 9;
    int ky = r / 3, kx = r - ky * 3;
    int oy = p >> 2, ox = p & 3;
    c1b[b * 4608 + i] = f2bf(c1s[ic * 36 + (oy + ky) * 6 + ox + kx]);
  }
}

// ---------------- k_pc: prep (blocks 0..511) + conv2 GEMM via MFMA (blocks 512..527) ----------------
// prep: CSR build + fcw->bf16 + W2 transpose/partials (round-2 code).
// conv2: M=64(oc) x K=288 x N=4096(img*16+pos), bf16 MFMA, no LDS.
__global__ __launch_bounds__(512, 2) void k_pc(
    const int* __restrict__ edges, const float* __restrict__ fcw,
    const float* __restrict__ g2w, const float* __restrict__ g2b,
    unsigned short* fcwbf, unsigned short* w2t, float* wpart, int* cnt, int* csr,
    const unsigned short* __restrict__ c1b, const unsigned short* __restrict__ w2abf,
    const float* __restrict__ c2b, unsigned short* h1024bf) {
  __shared__ float sm[288];  // prep: red[16][17] + b2s[16]
  int t = threadIdx.x;
  int wave = t >> 6, lane = t & 63;
  if (blockIdx.x < 512) {  // ---- prep ----
    float (*red)[17] = (float(*)[17])sm;
    float* b2s = sm + 272;
    int blk = blockIdx.x;
    {  // CSR: 1 edge per thread (512*512 = NE)
      int e = blk * 512 + t;
      int s = edges[2 * e], d = edges[2 * e + 1];
      int slot = atomicAdd(&cnt[d], 1);
      if (slot < CSR_CAP) csr[d * CSR_CAP + slot] = s;
    }
    {  // fcw -> bf16: 2 floats per thread
      int base = (blk * 512 + t) * 2;
      float2 v = *(const float2*)&fcw[base];
      fcwbf[base + 0] = f2bf(v.x);
      fcwbf[base + 1] = f2bf(v.y);
    }
    {  // W2: block owns 16 cols; w2t[j][k] = W2[k][j] bf16; column partial sums
      if (t < 256) {
        int jj = t >> 4, k = t & 15;
        int j = blk * 16 + jj;
        float w = g2w[k * 8192 + j];
        w2t[j * 16 + k] = f2bf(w);
        red[jj][k] = w;
      }
      if (t < 16) b2s[t] = g2b[blk * 16 + t];
      __syncthreads();
      if (t < 16) {
        float s = 0.0f;
#pragma unroll
        for (int q = 0; q < 16; q++) s += red[q][t];
        wpart[blk * 17 + t] = s;
      } else if (t == 16) {
        float s = 0.0f;
#pragma unroll
        for (int q = 0; q < 16; q++) s += b2s[q];
        wpart[blk * 17 + 16] = s;
      }
    }
  } else {  // ---- conv2 GEMM: block nb owns 256 cols of N; wave owns 32 ----
    int nb = blockIdx.x - 512;          // 0..15
    int nbase = nb * 256 + wave * 32;   // this wave's n-range
    int m = lane & 15, quad = lane >> 4;
    float4v z = {0.0f, 0.0f, 0.0f, 0.0f};
    float4v acc00 = z, acc01 = z, acc02 = z, acc03 = z;
    float4v acc10 = z, acc11 = z, acc12 = z, acc13 = z;
#pragma unroll
    for (int ks = 0; ks < 9; ks++) {
      int ko = ks * 32 + quad * 8;
      short8 a0 = *(const short8*)&w2abf[(0 * 16 + m) * 288 + ko];
      short8 a1 = *(const short8*)&w2abf[(1 * 16 + m) * 288 + ko];
      short8 a2 = *(const short8*)&w2abf[(2 * 16 + m) * 288 + ko];
      short8 a3 = *(const short8*)&w2abf[(3 * 16 + m) * 288 + ko];
      short8 b0 = *(const short8*)&c1b[(nbase + m) * 288 + ko];
      short8 b1 = *(const short8*)&c1b[(nbase + 16 + m) * 288 + ko];
      acc00 = __builtin_amdgcn_mfma_f32_16x16x32_bf16(a0, b0, acc00, 0, 0, 0);
      acc01 = __builtin_amdgcn_mfma_f32_16x16x32_bf16(a1, b0, acc01, 0, 0, 0);
      acc02 = __builtin_amdgcn_mfma_f32_16x16x32_bf16(a2, b0, acc02, 0, 0, 0);
      acc03 = __builtin_amdgcn_mfma_f32_16x16x32_bf16(a3, b0, acc03, 0, 0, 0);
      acc10 = __builtin_amdgcn_mfma_f32_16x16x32_bf16(a0, b1, acc10, 0, 0, 0);
      acc11 = __builtin_amdgcn_mfma_f32_16x16x32_bf16(a1, b1, acc11, 0, 0, 0);
      acc12 = __builtin_amdgcn_mfma_f32_16x16x32_bf16(a2, b1, acc12, 0, 0, 0);
      acc13 = __builtin_amdgcn_mfma_f32_16x16x32_bf16(a3, b1, acc13, 0, 0, 0);
    }
    float4v accs[2][4] = {{acc00, acc01, acc02, acc03}, {acc10, acc11, acc12, acc13}};
#pragma unroll
    for (int nt = 0; nt < 2; nt++) {
#pragma unroll
      for (int mt = 0; mt < 4; mt++) {
#pragma unroll
        for (int r = 0; r < 4; r++) {
          int oc = mt * 16 + quad * 4 + r;   // C/D row = A-side (oc)
          int n = nbase + nt * 16 + m;       // C/D col = B-side (img*16+pos)
          int img = n >> 4, pos = n & 15;
          h1024bf[img * 1024 + oc * 16 + pos] =
              f2bf(fmaxf(accs[nt][mt][r] + c2b[oc], 0.0f));
        }
      }
    }
  }
}

// ---------------- k_fc: FC via bf16 MFMA (1 tile/block, K-split 4) + dinv/xs2 + wsf ----------------
__global__ __launch_bounds__(256, 4) void k_fc(
    const int* __restrict__ cnt, const float* __restrict__ x_msg,
    const unsigned short* __restrict__ h1024bf, const unsigned short* __restrict__ fcwbf,
    const float* __restrict__ fcb, const float* __restrict__ wpart,
    float* hidden, float* dinv, float* xs2, float* wsf) {
  __shared__ float red[4][256];
  int t = threadIdx.x, blk = blockIdx.x;
  if (blk == 512) {  // parallel wsf reduce: 272 threads x 32 strided loads
    float* part = &red[0][0];
    if (t < 272) {
      int q = t / 17, c = t - q * 17;
      float s = 0.0f;
      for (int r = q; r < 512; r += 16) s += wpart[r * 17 + c];
      part[t] = s;
    }
    __syncthreads();
    if (t < 17) {
      float s = 0.0f;
#pragma unroll
      for (int q = 0; q < 16; q++) s += part[q * 17 + t];
      wsf[t] = s;
    }
    return;
  }
  int wave = t >> 6, lane = t & 63;
  if (blk < 32) {
    int i = blk * 256 + t;
    float d = rsqrtf((float)cnt[i] + 1.0f);
    dinv[i] = d;
    xs2[i] = d * x_msg[i];
  }
  int tr = blk >> 5, tc = blk & 31;  // 16 row-tiles x 32 col-tiles
  int m = lane & 15, quad = lane >> 4;
  const unsigned short* ap = &h1024bf[(tr * 16 + m) * 1024 + wave * 256 + quad * 8];
  const unsigned short* bp = &fcwbf[(tc * 16 + m) * 1024 + wave * 256 + quad * 8];
  float4v acc = {0.0f, 0.0f, 0.0f, 0.0f};
#pragma unroll
  for (int i = 0; i < 8; i++) {
    short8 a = *(const short8*)(ap + i * 32);
    short8 b = *(const short8*)(bp + i * 32);
    acc = __builtin_amdgcn_mfma_f32_16x16x32_bf16(a, b, acc, 0, 0, 0);
  }
#pragma unroll
  for (int r = 0; r < 4; r++) red[wave][(quad * 4 + r) * 16 + m] = acc[r];
  __syncthreads();
  {  // reduce 4 K-slices + bias + relu
    float s = red[0][t] + red[1][t] + red[2][t] + red[3][t];
    int gr = tr * 16 + (t >> 4);
    int gc = tc * 16 + (t & 15);
    hidden[gr * 512 + gc] = fmaxf(s + fcb[gc], 0.0f);
  }
}

// ---------------- k_he: head (blocks 0..63) | enc (blocks 64..511) ----------------
__global__ __launch_bounds__(512, 2) void k_he(
    const float* __restrict__ hidden, const float* __restrict__ muw,
    const float* __restrict__ mub, const float* __restrict__ msgw,
    const float* __restrict__ msgb, const float* __restrict__ dinv,
    const int* __restrict__ action, float* es2, float* out) {
  __shared__ float muT[10752];
  __shared__ float hrows[2048];
  int t = threadIdx.x, blk = blockIdx.x;
  int wave = t >> 6, lane = t & 63;
  if (blk < 64) {  // head: 4 batch rows per block
    int b0 = blk * 4;
    for (int i = t; i < 10752; i += 512) {
      int a = i >> 9, k = i & 511;
      muT[k * 21 + a] = muw[i];
    }
    for (int i = t; i < 2048; i += 512) hrows[i] = hidden[b0 * 512 + i];
    __syncthreads();
    if (wave < 4) {
      int b = b0 + wave;
      float logit = -1e30f;
      if (lane < NACT) {
        float acc = mub[lane];
        const float* hr = &hrows[wave * 512];
        for (int k = 0; k < 512; k++) acc += hr[k] * muT[k * 21 + lane];
        logit = acc;
      }
      float m = logit;
#pragma unroll
      for (int s = 32; s > 0; s >>= 1) m = fmaxf(m, __shfl_xor(m, s, 64));
      float e = (lane < NACT) ? __expf(logit - m) : 0.0f;
      float se = wsum64(e);
      float swl = wsum64(e * logit);
      float lse = m + __logf(se);
      int act = action[b];
      if (lane == 0) {
        out[b] = (float)act;                  // action passthrough
        out[8704 + b] = lse - swl / se;       // entropy
      }
      if (lane == act) out[8448 + b] = logit - lse;  // log_prob
    }
  } else {  // enc: es2[j] = dinv[j] * (hidden[0].msg_w[j] + msgb[j])
    int wg = (blk - 64) * 8 + wave;  // 0..3583
    for (int j = wg; j < NA; j += 3584) {
      const float* wp = &msgw[j * 512 + lane * 8];
      float4 w0 = *(const float4*)(wp);
      float4 w1 = *(const float4*)(wp + 4);
      float4 h0 = *(const float4*)&hidden[lane * 8];
      float4 h1 = *(const float4*)&hidden[lane * 8 + 4];
      float s = w0.x * h0.x + w0.y * h0.y + w0.z * h0.z + w0.w * h0.w +
                w1.x * h1.x + w1.y * h1.y + w1.z * h1.z + w1.w * h1.w;
      s = wsum64(s);
      if (lane == 0) es2[j] = dinv[j] * (s + msgb[j]);
    }
  }
}

// ---------------- k_g1: GCN1 gather (2 rows per wave, 512 blocks) ----------------
__global__ __launch_bounds__(512, 4) void k_g1(
    const int* __restrict__ cnt, const int* __restrict__ csr,
    const float* __restrict__ dinv, const float* __restrict__ xs2,
    const float* __restrict__ es2, const float* __restrict__ g1w,
    const float* __restrict__ g1b, float* gbuf2) {
  int t = threadIdx.x, blk = blockIdx.x;
  int wave = t >> 6, lane = t & 63;
  int wg = blk * 8 + wave;  // 0..4095
#pragma unroll
  for (int rr = 0; rr < 2; rr++) {
    int i = wg * 2 + rr;
    int ci = min(cnt[i], CSR_CAP);
    float di = dinv[i];
    float a0 = 0.0f, a1 = 0.0f;
    for (int e = lane; e < ci; e += 64) {
      int s = csr[i * CSR_CAP + e];
      a0 += xs2[s];
      a1 += es2[s];
    }
    // self-loop coeff di^2: di*(sum_s dinv[s]x[s] + dinv[i]x[i])
    float f0 = (wsum64(a0) + xs2[i]) * di;
    float f1 = (wsum64(a1) + es2[i]) * di;
    if (lane < 16) {
      float gv = fmaxf(f0 * g1w[lane] + f1 * g1w[16 + lane] + g1b[lane], 0.0f);
      gbuf2[i * 16 + lane] = di * gv;
    }
  }
}

// ---------------- k_msg: GCN2 gather + MFMA scores + sum-exp (16 rows/block, 512 blocks) ----------------
__global__ __launch_bounds__(512, 2) void k_msg(
    const int* __restrict__ cnt, const int* __restrict__ csr,
    const float* __restrict__ dinv, const float* __restrict__ gbuf2,
    const float* __restrict__ wsf, const unsigned short* __restrict__ w2t,
    const float* __restrict__ g2b, float* out) {
  __shared__ __align__(16) unsigned short vbf[256];
  __shared__ float vf[256];
  __shared__ float pl[2048];
  __shared__ float sl[128];
  __shared__ float wsfs[17];
  int t = threadIdx.x, blk = blockIdx.x;
  int wave = t >> 6, lane = t & 63;
  int rowbase = blk * 16;
  if (t < 17) wsfs[t] = wsf[t];
  {  // gather 16 V rows: 8 waves x 2 rows; lanes = 4 edge-groups x 16 cols
    int eq = lane >> 4, c = lane & 15;
#pragma unroll
    for (int rr = 0; rr < 2; rr++) {
      int il = wave * 2 + rr;
      int i = rowbase + il;
      int ci = min(cnt[i], CSR_CAP);
      float di = dinv[i];
      float acc = (eq == 0) ? gbuf2[i * 16 + c] : 0.0f;  // self: di*(...+gbuf2[i]) = di^2*g_i
      for (int e = eq; e < ci; e += 4) {
        int s = csr[i * CSR_CAP + e];
        acc += gbuf2[s * 16 + c];
      }
      acc *= di;
      acc += __shfl_xor(acc, 16, 64);
      acc += __shfl_xor(acc, 32, 64);
      if (eq == 0) {
        vf[il * 16 + c] = acc;
        vbf[il * 16 + c] = f2bf(acc * LOG2E);  // pre-scale for exp2
      }
    }
  }
  __syncthreads();
  float myMean = 0.0f;
  if (t < 16) {
    float dot = 0.0f;
#pragma unroll
    for (int c = 0; c < 16; c++) dot += vf[t * 16 + c] * wsfs[c];
    myMean = (dot + wsfs[16]) * (1.0f / 8192.0f);
  }
  {  // scores via MFMA (log2e-scaled) + exp2; each wave owns a 1024-col slice
    int quad = lane >> 4, n = lane & 15;
    int k8 = quad * 8;
    short8 za = {0, 0, 0, 0, 0, 0, 0, 0};
    short8 a1 = za;
    if (quad < 2) a1 = *(const short8*)&vbf[n * 16 + k8];  // K padded 16->32
    float sacc[4];
#pragma unroll
    for (int q = 0; q < 4; q++) sacc[q] = 0.0f;
    int colb = wave * 1024 + n;
    for (int tp = 0; tp < 64; tp += 2) {
      int col1 = colb + tp * 16;
      int col2 = col1 + 16;
      short8 b1 = za, b2 = za;
      if (quad < 2) {
        b1 = *(const short8*)&w2t[col1 * 16 + k8];
        b2 = *(const short8*)&w2t[col2 * 16 + k8];
      }
      float bb1 = g2b[col1] * LOG2E, bb2 = g2b[col2] * LOG2E;
      float4v c1 = {bb1, bb1, bb1, bb1};
      float4v c2 = {bb2, bb2, bb2, bb2};
      float4v s11 = __builtin_amdgcn_mfma_f32_16x16x32_bf16(a1, b1, c1, 0, 0, 0);
      float4v s12 = __builtin_amdgcn_mfma_f32_16x16x32_bf16(a1, b2, c2, 0, 0, 0);
#pragma unroll
      for (int r = 0; r < 4; r++) sacc[r] += EXP2F(s11[r]) + EXP2F(s12[r]);
    }
#pragma unroll
    for (int q = 0; q < 4; q++) {
      int rl = quad * 4 + q;  // C/D row = quad*4+reg
      pl[rl * 128 + wave * 16 + n] = sacc[q];
    }
  }
  __syncthreads();
  if (t < 128) {
    int r = t >> 3, seg = t & 7;
    int base = r * 128 + seg * 16;
    float ll = 0.0f;
#pragma unroll
    for (int i = 0; i < 16; i++) ll += pl[base + i];
    sl[r * 8 + seg] = ll;
  }
  __syncthreads();
  if (t < 16) {
    float ll = 0.0f;
#pragma unroll
    for (int i = 0; i < 8; i++) ll += sl[t * 8 + i];
    out[256 + rowbase + t] = myMean - __logf(ll);  // ll = sum exp(s)
  }
}

extern "C" void kernel_launch(void* const* d_in, const int* in_sizes, int n_in,
                              void* d_out, int out_size, void* d_ws, size_t ws_size,
                              hipStream_t stream) {
  const float* x     = (const float*)d_in[0];
  const float* x_msg = (const float*)d_in[1];
  const int*   edges = (const int*)d_in[2];
  const int*   action= (const int*)d_in[3];
  const float* c1w   = (const float*)d_in[4];
  const float* c1bb  = (const float*)d_in[5];
  const float* c2w   = (const float*)d_in[6];
  const float* c2b   = (const float*)d_in[7];
  const float* fcw   = (const float*)d_in[8];
  const float* fcb   = (const float*)d_in[9];
  const float* muw   = (const float*)d_in[10];
  const float* mub   = (const float*)d_in[11];
  const float* msgw  = (const float*)d_in[12];
  const float* msgb  = (const float*)d_in[13];
  const float* g1w   = (const float*)d_in[14];
  const float* g1b   = (const float*)d_in[15];
  const float* g2w   = (const float*)d_in[16];
  const float* g2b   = (const float*)d_in[17];
  float* out = (float*)d_out;  // reference outputs are fp32

  float* ws     = (float*)d_ws;
  unsigned short* h1024bf = (unsigned short*)ws;            // 262144 bf16 = 131072 f
  unsigned short* fcwbf   = (unsigned short*)(ws + 131072); // 524288 bf16 = 262144 f
  float* hidden = ws + 393216;           // 131072
  float* es2    = ws + 524288;           // 8192
  float* dinv   = ws + 532480;           // 8192
  float* xs2    = ws + 540672;           // 8192
  float* gbuf2  = ws + 548864;           // 131072
  float* wpart  = ws + 679936;           // 8704
  unsigned short* w2t = (unsigned short*)(ws + 688640);     // 131072 bf16 = 65536 f
  int*   cnt    = (int*)(ws + 754176);   // 8192 ints
  int*   csr    = (int*)(ws + 762368);   // 1048576 ints -> ends at float-offset 1810944
  float* wsf    = ws + 1810944;          // 17
  unsigned short* c1b   = (unsigned short*)(ws + 1810964);  // 4096*288 bf16 = 589824 f
  unsigned short* w2abf = (unsigned short*)(ws + 2400788);  // 64*288 bf16 = 9216 f

  k_ic <<<308, 512, 0, stream>>>(x, c1w, c1bb, c2w, c1b, w2abf, cnt);
  k_pc <<<528, 512, 0, stream>>>(edges, fcw, g2w, g2b, fcwbf, w2t, wpart, cnt, csr,
                                 c1b, w2abf, c2b, h1024bf);
  k_fc <<<513, 256, 0, stream>>>(cnt, x_msg, h1024bf, fcwbf, fcb, wpart, hidden, dinv, xs2, wsf);
  k_he <<<512, 512, 0, stream>>>(hidden, muw, mub, msgw, msgb, dinv, action, es2, out);
  k_g1 <<<512, 512, 0, stream>>>(cnt, csr, dinv, xs2, es2, g1w, g1b, gbuf2);
  k_msg<<<512, 512, 0, stream>>>(cnt, csr, dinv, gbuf2, wsf, w2t, g2b, out);
}